// Round 4
// baseline (2387.612 us; speedup 1.0000x reference)
//
#include <hip/hip_runtime.h>
#include <hip/hip_bf16.h>

// ---------------------------------------------------------------------------
// Gemma2 attention layer: qkv proj -> rope -> causal GQA attn (softcap) -> o proj
// T=2048 HID=3584 NH=16 NKV=8 HD=256
// Inputs: positions int32, hidden/w_qkv/w_o FP32. Output: FP32 (reference dtype).
// Intermediates (qkv, attn) bf16 in d_ws; GEMMs = MFMA 16x16x32 bf16
// (validated: round2 MFMA == round3 VALU bit-identical downstream).
// ---------------------------------------------------------------------------

#define T_SEQ 2048
#define HID_DIM 3584
#define NH 16
#define NKV 8
#define HD 256
#define QKV_N ((NH + 2 * NKV) * HD)   // 8192
#define ATT_N (NH * HD)               // 4096

typedef __bf16 bf16_t;
typedef bf16_t bf16x8 __attribute__((ext_vector_type(8)));
typedef float f32x4 __attribute__((ext_vector_type(4)));

__device__ __forceinline__ float bf2f(unsigned short u) {
  union { unsigned int i; float f; } v;
  v.i = ((unsigned int)u) << 16;
  return v.f;
}

// --- staging load helpers: 8 contiguous elements -> bf16x8 -----------------
__device__ __forceinline__ bf16x8 loadA8(const float* p) {
  const float4 f0 = *(const float4*)p;
  const float4 f1 = *(const float4*)(p + 4);
  bf16x8 v;
  v[0] = (bf16_t)f0.x; v[1] = (bf16_t)f0.y; v[2] = (bf16_t)f0.z; v[3] = (bf16_t)f0.w;
  v[4] = (bf16_t)f1.x; v[5] = (bf16_t)f1.y; v[6] = (bf16_t)f1.z; v[7] = (bf16_t)f1.w;
  return v;
}
__device__ __forceinline__ bf16x8 loadA8(const bf16_t* p) {
  return *(const bf16x8*)p;
}
__device__ __forceinline__ float ldf(const float* p) { return *p; }
__device__ __forceinline__ float ldf(const bf16_t* p) { return (float)*p; }

// ---------------------------------------------------------------------------
// GEMM: C[M,N] = A[M,K] @ B[K,N]; A,B fp32 or bf16; C fp32 or bf16;
// fp32 accum via MFMA 16x16x32 bf16. Block = 256 (4 waves), BM=BN=64, BK=32.
// Requires M%64==0, N%64==0, K%32==0 (true for both uses).
// ---------------------------------------------------------------------------
template <typename TA, typename TB, typename TC>
__global__ __launch_bounds__(256) void gemm_mfma(
    const TA* __restrict__ A, const TB* __restrict__ B,
    TC* __restrict__ C, int M, int N, int K) {
  const int n0 = blockIdx.x * 64;
  const int m0 = blockIdx.y * 64;
  const int t = threadIdx.x;
  const int wave = t >> 6;
  const int lane = t & 63;
  const int l16 = lane & 15;
  const int quad = lane >> 4;

  // LDS tiles: As[m][k], Bs[n][k] (B transposed). Row stride 40 keeps 16B
  // alignment for b128 access and breaks the stride-32 bank walk.
  __shared__ __align__(16) bf16_t As[64][40];
  __shared__ __align__(16) bf16_t Bs[64][40];

  f32x4 acc[4] = {f32x4{0,0,0,0}, f32x4{0,0,0,0}, f32x4{0,0,0,0}, f32x4{0,0,0,0}};

  // A staging: thread -> (row = t/4, 8-elem col seg).
  const int a_r = t >> 2;
  const int a_c = (t & 3) * 8;
  // B staging: thread -> (n = t&63, k-group = 8*(t>>6)); strided global loads
  // (coalesced across lanes per j), one contiguous b128 LDS write.
  const int b_n = t & 63;
  const int b_kg = (t >> 6) * 8;

  const TA* Aptr = A + (long)(m0 + a_r) * K + a_c;
  const TB* Bptr = B + (long)b_kg * N + n0 + b_n;

  for (int k0 = 0; k0 < K; k0 += 32) {
    *(bf16x8*)&As[a_r][a_c] = loadA8(Aptr);
    bf16x8 tmpv;
#pragma unroll
    for (int j = 0; j < 8; ++j) tmpv[j] = (bf16_t)ldf(Bptr + (long)j * N);
    *(bf16x8*)&Bs[b_n][b_kg] = tmpv;
    __syncthreads();

    // A-operand [m=lane&15][k=quad*8+j]; B-operand [n=lane&15][k=quad*8+j]
    bf16x8 af = *(const bf16x8*)&As[16 * wave + l16][quad * 8];
#pragma unroll
    for (int nt = 0; nt < 4; ++nt) {
      bf16x8 bfr = *(const bf16x8*)&Bs[16 * nt + l16][quad * 8];
      acc[nt] = __builtin_amdgcn_mfma_f32_16x16x32_bf16(af, bfr, acc[nt], 0, 0, 0);
    }
    __syncthreads();
    Aptr += 32;
    Bptr += (long)32 * N;
  }

  // C/D layout: col = lane&15, row = quad*4 + reg   [m89/m91 verified]
#pragma unroll
  for (int nt = 0; nt < 4; ++nt) {
    const int col = n0 + 16 * nt + l16;
#pragma unroll
    for (int r = 0; r < 4; ++r) {
      const int row = m0 + 16 * wave + quad * 4 + r;
      C[(long)row * N + col] = (TC)acc[nt][r];
    }
  }
}

// ---------------------------------------------------------------------------
// Neox-style RoPE over full HD=256, in-place on bf16 qkv (q: 16 heads, k: 8).
// ---------------------------------------------------------------------------
__global__ void rope_kernel(const int* __restrict__ positions,
                            bf16_t* __restrict__ qkv) {
  const int head = blockIdx.x;   // 0..23 : 0..15 q heads, 16..23 k heads
  const int trow = blockIdx.y;   // 0..2047
  const int d = threadIdx.x;     // 0..127 (pairs with d+128)
  const long col0 = (head < NH) ? (long)head * HD
                                : (long)(NH * HD) + (long)(head - NH) * HD;
  bf16_t* p = qkv + (long)trow * QKV_N + col0;
  const float pos = (float)positions[trow];
  // inv_freq = 10000^(-d/128) = 2^(-d * log2(10000)/128)
  const float inv_freq = exp2f(-(float)d * (13.287712379549449f / 128.0f));
  const float ang = pos * inv_freq;
  float s, c;
  sincosf(ang, &s, &c);
  const float x1 = (float)p[d];
  const float x2 = (float)p[d + 128];
  p[d]       = (bf16_t)(x1 * c - x2 * s);
  p[d + 128] = (bf16_t)(x2 * c + x1 * s);
}

// ---------------------------------------------------------------------------
// Flash-style causal GQA attention, VALU (unchanged; optimize next round).
// Block = 256: one (head, 32 q-rows) tile; iterate 32-key tiles.
// Thread (tq=t>>3, tk=t&7): scores S[tq][tk*4..+3]; PV accumulates dims
// [tk*32, tk*32+32) of O[tq]. Online softmax replicated across 8-lane group.
// ---------------------------------------------------------------------------
#define TQ 32
#define KT 32
#define DPAD 260

__global__ __launch_bounds__(256) void attn_kernel(
    const bf16_t* __restrict__ qkv, bf16_t* __restrict__ out /* [T, 4096] */) {
  const int h = blockIdx.x;
  const int q0 = blockIdx.y * TQ;
  const int t = threadIdx.x;
  const int tq = t >> 3;
  const int tk = t & 7;

  __shared__ __align__(16) unsigned short Qs[TQ * DPAD];
  __shared__ __align__(16) unsigned short Ks[KT * DPAD];
  __shared__ __align__(16) unsigned short Vs[KT * DPAD];
  __shared__ float Ps[TQ][KT + 1];

  const int kvh = h >> 1;               // GQA: q head h uses kv head h/2
  const long qcol = (long)h * HD;
  const long kcol = (long)NH * HD + (long)kvh * HD;
  const long vcol = (long)(NH + NKV) * HD + (long)kvh * HD;

#pragma unroll
  for (int i = 0; i < 8; ++i) {
    const int idx = i * 256 + t;
    const int r = idx >> 6;
    const int dseg = (idx & 63) * 4;
    *(ushort4*)&Qs[r * DPAD + dseg] =
        *(const ushort4*)(qkv + (long)(q0 + r) * QKV_N + qcol + dseg);
  }

  float m_i = -1e30f, l_i = 0.0f;
  float o_acc[32];
#pragma unroll
  for (int i = 0; i < 32; ++i) o_acc[i] = 0.0f;
  const int d0 = tk * 32;

  const int ktiles = q0 / KT + 1;
  for (int kt = 0; kt < ktiles; ++kt) {
    const int j0 = kt * KT;
    __syncthreads();  // previous iteration done with Ks/Vs
#pragma unroll
    for (int i = 0; i < 8; ++i) {
      const int idx = i * 256 + t;
      const int r = idx >> 6;
      const int dseg = (idx & 63) * 4;
      *(ushort4*)&Ks[r * DPAD + dseg] =
          *(const ushort4*)(qkv + (long)(j0 + r) * QKV_N + kcol + dseg);
      *(ushort4*)&Vs[r * DPAD + dseg] =
          *(const ushort4*)(qkv + (long)(j0 + r) * QKV_N + vcol + dseg);
    }
    __syncthreads();

    float s[4] = {0.f, 0.f, 0.f, 0.f};
    const unsigned short* qrow = &Qs[tq * DPAD];
    for (int d = 0; d < 256; d += 4) {
      const ushort4 qv = *(const ushort4*)&qrow[d];
      const float q0f = bf2f(qv.x), q1f = bf2f(qv.y), q2f = bf2f(qv.z), q3f = bf2f(qv.w);
#pragma unroll
      for (int jj = 0; jj < 4; ++jj) {
        const ushort4 kv = *(const ushort4*)&Ks[(tk * 4 + jj) * DPAD + d];
        s[jj] += q0f * bf2f(kv.x) + q1f * bf2f(kv.y) + q2f * bf2f(kv.z) + q3f * bf2f(kv.w);
      }
    }

    float smax = -1e30f;
#pragma unroll
    for (int jj = 0; jj < 4; ++jj) {
      const int j = j0 + tk * 4 + jj;
      float sc = 50.0f * tanhf(s[jj] * (0.0625f / 50.0f));
      sc = (j <= q0 + tq) ? sc : -1e30f;
      s[jj] = sc;
      smax = fmaxf(smax, sc);
    }
#pragma unroll
    for (int off = 1; off < 8; off <<= 1)
      smax = fmaxf(smax, __shfl_xor(smax, off, 64));
    const float m_new = fmaxf(m_i, smax);
    float psum = 0.0f;
#pragma unroll
    for (int jj = 0; jj < 4; ++jj) {
      const float p = (s[jj] > -1e29f) ? __expf(s[jj] - m_new) : 0.0f;
      Ps[tq][tk * 4 + jj] = p;
      psum += p;
    }
#pragma unroll
    for (int off = 1; off < 8; off <<= 1)
      psum += __shfl_xor(psum, off, 64);
    const float alpha = __expf(m_i - m_new);
    l_i = l_i * alpha + psum;
    m_i = m_new;
#pragma unroll
    for (int i = 0; i < 32; ++i) o_acc[i] *= alpha;
    __syncthreads();

    for (int j = 0; j < KT; ++j) {
      const float p = Ps[tq][j];
      const unsigned short* vrow = &Vs[j * DPAD + d0];
#pragma unroll
      for (int dd = 0; dd < 32; dd += 4) {
        const ushort4 vv = *(const ushort4*)&vrow[dd];
        o_acc[dd]     += p * bf2f(vv.x);
        o_acc[dd + 1] += p * bf2f(vv.y);
        o_acc[dd + 2] += p * bf2f(vv.z);
        o_acc[dd + 3] += p * bf2f(vv.w);
      }
    }
  }

  const float inv_l = 1.0f / l_i;
  bf16_t* orow = out + (long)(q0 + tq) * ATT_N + (long)h * HD + d0;
#pragma unroll
  for (int i = 0; i < 32; ++i) orow[i] = (bf16_t)(o_acc[i] * inv_l);
}

// ---------------------------------------------------------------------------
extern "C" void kernel_launch(void* const* d_in, const int* in_sizes, int n_in,
                              void* d_out, int out_size, void* d_ws, size_t ws_size,
                              hipStream_t stream) {
  const int* positions = (const int*)d_in[0];
  const float* hidden = (const float*)d_in[1];   // fp32 per reference
  const float* w_qkv = (const float*)d_in[2];    // fp32 per reference
  const float* w_o = (const float*)d_in[3];      // fp32 per reference
  float* out = (float*)d_out;                    // FP32 — reference output dtype

  bf16_t* qkv = (bf16_t*)d_ws;                          // [2048, 8192] bf16
  bf16_t* attn = qkv + (size_t)T_SEQ * QKV_N;           // [2048, 4096] bf16

  // 1) qkv = hidden @ w_qkv  (fp32 in -> bf16 out)
  gemm_mfma<float, float, bf16_t>
      <<<dim3(QKV_N / 64, T_SEQ / 64), 256, 0, stream>>>(
          hidden, w_qkv, qkv, T_SEQ, QKV_N, HID_DIM);
  // 2) rope on q,k in-place
  rope_kernel<<<dim3(NH + NKV, T_SEQ), 128, 0, stream>>>(positions, qkv);
  // 3) attention
  attn_kernel<<<dim3(NH, T_SEQ / TQ), 256, 0, stream>>>(qkv, attn);
  // 4) out = attn @ w_o  (bf16 x fp32 -> FP32 out)
  gemm_mfma<bf16_t, float, float>
      <<<dim3(HID_DIM / 64, T_SEQ / 64), 256, 0, stream>>>(
          attn, w_o, out, T_SEQ, HID_DIM, ATT_N);
}

// Round 5
// 1179.082 us; speedup vs baseline: 2.0250x; 2.0250x over previous
//
#include <hip/hip_runtime.h>
#include <hip/hip_bf16.h>

// ---------------------------------------------------------------------------
// Gemma2 attention layer: qkv proj -> rope -> causal GQA attn (softcap) -> o proj
// T=2048 HID=3584 NH=16 NKV=8 HD=256
// Inputs: positions int32, hidden/w_qkv/w_o FP32. Output: FP32.
// R5: MFMA attention. QKV GEMM writes V transposed into the (otherwise unused)
// V slot of the qkv buffer; attention does QK^T and PV on matrix cores with
// K/V fragments read directly from global (L2-served), P round-tripped
// through LDS (C-layout -> A-layout).
// ---------------------------------------------------------------------------

#define T_SEQ 2048
#define HID_DIM 3584
#define NH 16
#define NKV 8
#define HD 256
#define QKV_N ((NH + 2 * NKV) * HD)   // 8192
#define ATT_N (NH * HD)               // 4096
#define V_OFF ((NH + NKV) * HD)       // 6144

typedef __bf16 bf16_t;
typedef bf16_t bf16x8 __attribute__((ext_vector_type(8)));
typedef float f32x4 __attribute__((ext_vector_type(4)));

// --- staging load helpers: 8 contiguous elements -> bf16x8 -----------------
__device__ __forceinline__ bf16x8 loadA8(const float* p) {
  const float4 f0 = *(const float4*)p;
  const float4 f1 = *(const float4*)(p + 4);
  bf16x8 v;
  v[0] = (bf16_t)f0.x; v[1] = (bf16_t)f0.y; v[2] = (bf16_t)f0.z; v[3] = (bf16_t)f0.w;
  v[4] = (bf16_t)f1.x; v[5] = (bf16_t)f1.y; v[6] = (bf16_t)f1.z; v[7] = (bf16_t)f1.w;
  return v;
}
__device__ __forceinline__ bf16x8 loadA8(const bf16_t* p) {
  return *(const bf16x8*)p;
}
__device__ __forceinline__ float ldf(const float* p) { return *p; }
__device__ __forceinline__ float ldf(const bf16_t* p) { return (float)*p; }

// ---------------------------------------------------------------------------
// GEMM: C[M,N] = A[M,K] @ B[K,N]; fp32 accum via MFMA 16x16x32 bf16.
// Columns >= voff are written TRANSPOSED to Vt[(col-voff)*QKV_N + row]
// (used to produce V^T for the attention PV stage). voff >= N disables.
// Block 256 (4 waves), BM=BN=64, BK=32. M%64==0, N%64==0, K%32==0.
// ---------------------------------------------------------------------------
template <typename TA, typename TB, typename TC>
__global__ __launch_bounds__(256) void gemm_mfma(
    const TA* __restrict__ A, const TB* __restrict__ B,
    TC* __restrict__ C, bf16_t* __restrict__ Vt, int voff,
    int M, int N, int K) {
  const int n0 = blockIdx.x * 64;
  const int m0 = blockIdx.y * 64;
  const int t = threadIdx.x;
  const int wave = t >> 6;
  const int lane = t & 63;
  const int l16 = lane & 15;
  const int quad = lane >> 4;

  __shared__ __align__(16) bf16_t As[64][40];
  __shared__ __align__(16) bf16_t Bs[64][40];

  f32x4 acc[4] = {f32x4{0,0,0,0}, f32x4{0,0,0,0}, f32x4{0,0,0,0}, f32x4{0,0,0,0}};

  const int a_r = t >> 2;
  const int a_c = (t & 3) * 8;
  const int b_n = t & 63;
  const int b_kg = (t >> 6) * 8;

  const TA* Aptr = A + (long)(m0 + a_r) * K + a_c;
  const TB* Bptr = B + (long)b_kg * N + n0 + b_n;

  for (int k0 = 0; k0 < K; k0 += 32) {
    *(bf16x8*)&As[a_r][a_c] = loadA8(Aptr);
    bf16x8 tmpv;
#pragma unroll
    for (int j = 0; j < 8; ++j) tmpv[j] = (bf16_t)ldf(Bptr + (long)j * N);
    *(bf16x8*)&Bs[b_n][b_kg] = tmpv;
    __syncthreads();

    bf16x8 af = *(const bf16x8*)&As[16 * wave + l16][quad * 8];
#pragma unroll
    for (int nt = 0; nt < 4; ++nt) {
      bf16x8 bfr = *(const bf16x8*)&Bs[16 * nt + l16][quad * 8];
      acc[nt] = __builtin_amdgcn_mfma_f32_16x16x32_bf16(af, bfr, acc[nt], 0, 0, 0);
    }
    __syncthreads();
    Aptr += 32;
    Bptr += (long)32 * N;
  }

  // C/D layout: col = lane&15, row = quad*4 + reg
#pragma unroll
  for (int nt = 0; nt < 4; ++nt) {
    const int col = n0 + 16 * nt + l16;
#pragma unroll
    for (int r = 0; r < 4; ++r) {
      const int row = m0 + 16 * wave + quad * 4 + r;
      if (col >= voff)
        Vt[(long)(col - voff) * QKV_N + row] = (bf16_t)acc[nt][r];
      else
        C[(long)row * N + col] = (TC)acc[nt][r];
    }
  }
}

// ---------------------------------------------------------------------------
// Neox-style RoPE over full HD=256, in-place on bf16 qkv (q: 16 heads, k: 8).
// V is untouched (it lives transposed in the V slot and needs no rope).
// ---------------------------------------------------------------------------
__global__ void rope_kernel(const int* __restrict__ positions,
                            bf16_t* __restrict__ qkv) {
  const int head = blockIdx.x;   // 0..23 : 0..15 q heads, 16..23 k heads
  const int trow = blockIdx.y;
  const int d = threadIdx.x;     // 0..127 (pairs with d+128)
  const long col0 = (head < NH) ? (long)head * HD
                                : (long)(NH * HD) + (long)(head - NH) * HD;
  bf16_t* p = qkv + (long)trow * QKV_N + col0;
  const float pos = (float)positions[trow];
  const float inv_freq = exp2f(-(float)d * (13.287712379549449f / 128.0f));
  const float ang = pos * inv_freq;
  float s, c;
  sincosf(ang, &s, &c);
  const float x1 = (float)p[d];
  const float x2 = (float)p[d + 128];
  p[d]       = (bf16_t)(x1 * c - x2 * s);
  p[d + 128] = (bf16_t)(x2 * c + x1 * s);
}

// ---------------------------------------------------------------------------
// MFMA flash attention. Block = 256 (4 waves) = one (head, 32 q-rows) tile.
// Wave w: wq=w&1 (q sub-tile), wk=w>>1. Per 32-key tile:
//   QK^T: S(wq,wk) 16x16 via 8 MFMAs; A=Q frags (regs), B=K frags (global/L2).
//   softcap+causal+online softmax in C-layout regs; cross-wave via LDS.
//   P -> LDS (C-layout write, A-layout read).
//   PV: O(wq, d=wk*128..+127) 8 MFMAs; B = V^T frags prefetched from global.
// ---------------------------------------------------------------------------
__global__ __launch_bounds__(256) void attn_mfma(
    const bf16_t* __restrict__ qkv, const bf16_t* __restrict__ vt,
    bf16_t* __restrict__ out /* [T, 4096] */) {
  const int h = blockIdx.x;
  const int q0 = blockIdx.y * 32;
  const int t = threadIdx.x;
  const int w = t >> 6;
  const int lane = t & 63;
  const int l16 = lane & 15;
  const int quad = lane >> 4;
  const int wq = w & 1;
  const int wk = w >> 1;
  const int kvh = h >> 1;

  __shared__ __align__(16) bf16_t Ps[32][40];
  __shared__ float pmax[2][32];
  __shared__ float ppsum[2][32];

  // Q A-frags: A[m=l16][k=quad*8+j], k runs over d (8 steps of 32).
  bf16x8 qf[8];
  {
    const bf16_t* qbase =
        qkv + (long)(q0 + wq * 16 + l16) * QKV_N + h * HD + quad * 8;
#pragma unroll
    for (int s = 0; s < 8; ++s) qf[s] = *(const bf16x8*)(qbase + s * 32);
  }

  const bf16_t* kbase =
      qkv + (long)(wk * 16 + l16) * QKV_N + NH * HD + kvh * HD + quad * 8;
  const bf16_t* vbase =
      vt + (long)(kvh * HD + wk * 128 + l16) * QKV_N + quad * 8;

  f32x4 oacc[8];
#pragma unroll
  for (int nt = 0; nt < 8; ++nt) oacc[nt] = f32x4{0, 0, 0, 0};
  float m_state[4], l_state[4];
#pragma unroll
  for (int r = 0; r < 4; ++r) { m_state[r] = -1e30f; l_state[r] = 0.0f; }

  const int ktiles = q0 / 32 + 1;
  for (int kt = 0; kt < ktiles; ++kt) {
    // Prefetch V^T B-frags early: B[n=d][k=key], 8 contiguous keys per lane.
    bf16x8 vf[8];
    {
      const bf16_t* vp = vbase + kt * 32;
#pragma unroll
      for (int nt = 0; nt < 8; ++nt)
        vf[nt] = *(const bf16x8*)(vp + (long)nt * 16 * QKV_N);
    }
    // K B-frags: B[n=key16][k=d], 8 d-steps.
    f32x4 sacc = f32x4{0, 0, 0, 0};
    {
      const bf16_t* kp = kbase + (long)kt * 32 * QKV_N;
#pragma unroll
      for (int s = 0; s < 8; ++s) {
        bf16x8 kf = *(const bf16x8*)(kp + s * 32);
        sacc = __builtin_amdgcn_mfma_f32_16x16x32_bf16(qf[s], kf, sacc, 0, 0, 0);
      }
    }

    // softcap + causal mask + per-16-col rowmax (C-layout: row=quad*4+r, col=l16)
    float sv[4], rmax[4];
#pragma unroll
    for (int r = 0; r < 4; ++r) {
      const float x = sacc[r] * 0.0625f;
      const float e = __expf(x * 0.04f);          // e^(2x/50)
      float tz = 50.0f * (e - 1.0f) / (e + 1.0f); // 50*tanh(x/50)
      const int row = q0 + wq * 16 + quad * 4 + r;
      const int col = kt * 32 + wk * 16 + l16;
      sv[r] = (col <= row) ? tz : -1e30f;
      float rm = sv[r];
      rm = fmaxf(rm, __shfl_xor(rm, 1));
      rm = fmaxf(rm, __shfl_xor(rm, 2));
      rm = fmaxf(rm, __shfl_xor(rm, 4));
      rm = fmaxf(rm, __shfl_xor(rm, 8));
      rmax[r] = rm;
    }
    if (l16 == 0) {
#pragma unroll
      for (int r = 0; r < 4; ++r) pmax[wk][wq * 16 + quad * 4 + r] = rmax[r];
    }
    __syncthreads();

    float mnew[4], psum[4];
#pragma unroll
    for (int r = 0; r < 4; ++r) {
      const int ridx = wq * 16 + quad * 4 + r;
      const float mt = fmaxf(pmax[0][ridx], pmax[1][ridx]);
      mnew[r] = fmaxf(m_state[r], mt);
      const float p = (sv[r] > -1e29f) ? __expf(sv[r] - mnew[r]) : 0.0f;
      Ps[ridx][wk * 16 + l16] = (bf16_t)p;
      float ps = p;
      ps += __shfl_xor(ps, 1);
      ps += __shfl_xor(ps, 2);
      ps += __shfl_xor(ps, 4);
      ps += __shfl_xor(ps, 8);
      psum[r] = ps;
    }
    if (l16 == 0) {
#pragma unroll
      for (int r = 0; r < 4; ++r) ppsum[wk][wq * 16 + quad * 4 + r] = psum[r];
    }
    __syncthreads();

#pragma unroll
    for (int r = 0; r < 4; ++r) {
      const int ridx = wq * 16 + quad * 4 + r;
      const float tot = ppsum[0][ridx] + ppsum[1][ridx];
      const float alpha = __expf(m_state[r] - mnew[r]);
      l_state[r] = l_state[r] * alpha + tot;
      m_state[r] = mnew[r];
#pragma unroll
      for (int nt = 0; nt < 8; ++nt) oacc[nt][r] *= alpha;
    }

    // PV: A-frag = P rows wq*16+l16, keys quad*8..+7 (one b128 per wave).
    const bf16x8 pa = *(const bf16x8*)&Ps[wq * 16 + l16][quad * 8];
#pragma unroll
    for (int nt = 0; nt < 8; ++nt)
      oacc[nt] = __builtin_amdgcn_mfma_f32_16x16x32_bf16(pa, vf[nt], oacc[nt], 0, 0, 0);
  }

  // Epilogue: O row = q0+wq*16+quad*4+r, col = h*HD + wk*128 + nt*16 + l16.
#pragma unroll
  for (int r = 0; r < 4; ++r) {
    const float inv = 1.0f / l_state[r];
    const long row = q0 + wq * 16 + quad * 4 + r;
    bf16_t* op = out + row * ATT_N + h * HD + wk * 128 + l16;
#pragma unroll
    for (int nt = 0; nt < 8; ++nt) op[nt * 16] = (bf16_t)(oacc[nt][r] * inv);
  }
}

// ---------------------------------------------------------------------------
extern "C" void kernel_launch(void* const* d_in, const int* in_sizes, int n_in,
                              void* d_out, int out_size, void* d_ws, size_t ws_size,
                              hipStream_t stream) {
  const int* positions = (const int*)d_in[0];
  const float* hidden = (const float*)d_in[1];
  const float* w_qkv = (const float*)d_in[2];
  const float* w_o = (const float*)d_in[3];
  float* out = (float*)d_out;

  bf16_t* qkv = (bf16_t*)d_ws;                 // [2048, 8192] bf16 (Q|K|Vslot)
  bf16_t* attn = qkv + (size_t)T_SEQ * QKV_N;  // [2048, 4096] bf16
  bf16_t* vtb = qkv + V_OFF;  // V^T lives in the V slot: vt(d,t)=vtb[d*8192+t]

  // 1) qkv = hidden @ w_qkv; V columns routed transposed into vtb.
  gemm_mfma<float, float, bf16_t>
      <<<dim3(QKV_N / 64, T_SEQ / 64), 256, 0, stream>>>(
          hidden, w_qkv, qkv, vtb, V_OFF, T_SEQ, QKV_N, HID_DIM);
  // 2) rope on q,k in-place (V slot untouched)
  rope_kernel<<<dim3(NH + NKV, T_SEQ), 128, 0, stream>>>(positions, qkv);
  // 3) MFMA flash attention
  attn_mfma<<<dim3(NH, T_SEQ / 32), 256, 0, stream>>>(qkv, vtb, attn);
  // 4) out = attn @ w_o
  gemm_mfma<bf16_t, float, float>
      <<<dim3(HID_DIM / 64, T_SEQ / 64), 256, 0, stream>>>(
          attn, w_o, out, attn /*unused*/, 1 << 30, T_SEQ, HID_DIM, ATT_N);
}